// Round 17
// baseline (578.059 us; speedup 1.0000x reference)
//
#include <hip/hip_runtime.h>
#include <math.h>
#include <stdint.h>

#define B_ 8
#define N_ 2048
#define K_ 20
#define EPSV 1e-5f
#define SLOPEV 0.2f
#define TP_ 16     // points per edge_assemble block
#define NCOPY 32   // accumulator copies (atomic contention /32)

typedef unsigned short u16;
typedef unsigned long long u64;
typedef __attribute__((ext_vector_type(8))) short s8v;   // 8 x bf16 MFMA fragment
typedef __attribute__((ext_vector_type(4))) float f4v;   // 4 x f32 MFMA accumulator

static __device__ __forceinline__ float leakyf(float v){ return v >= 0.f ? v : SLOPEV*v; }

// float -> bf16 round-nearest-even, and back
static __device__ __forceinline__ u16 f2bf(float f){
  unsigned u = __float_as_uint(f);
  return (u16)((u + 0x7fffu + ((u >> 16) & 1u)) >> 16);
}
static __device__ __forceinline__ float bf2f(u16 h){ return __uint_as_float(((unsigned)h) << 16); }

// monotonic float->uint key (ascending)
static __device__ __forceinline__ unsigned fkey(float f){
  unsigned u = __float_as_uint(f);
  return u ^ ((u >> 31) ? 0xFFFFFFFFu : 0x80000000u);
}

static __device__ __forceinline__ void split3(float x, u16& h, u16& m, u16& l){
  h = f2bf(x);
  float r1 = x - bf2f(h);        // exact (Sterbenz)
  m = f2bf(r1);
  l = f2bf(r1 - bf2f(m));
}

// ---------------- fused input prep: transpose (B,3,N) + sqnorm + 3-plane split (Cout=32) --------
__global__ void k_in_prep(const float* __restrict__ x, float* __restrict__ xx,
                          u16* __restrict__ ph, u16* __restrict__ pm, u16* __restrict__ pl){
  int id = blockIdx.x*256 + threadIdx.x;
  if (id >= B_*N_) return;
  int b = id / N_, n = id % N_;
  float v0 = x[((size_t)b*3+0)*N_ + n];
  float v1 = x[((size_t)b*3+1)*N_ + n];
  float v2 = x[((size_t)b*3+2)*N_ + n];
  xx[id] = fmaf(v2, v2, fmaf(v1, v1, v0*v0));   // same order as old serial sqnorm
  u16 h0,m0,l0,h1,m1,l1,h2,m2,l2;
  split3(v0,h0,m0,l0); split3(v1,h1,m1,l1); split3(v2,h2,m2,l2);
  uint4 z4 = {0,0,0,0};
  uint4 w;
  w.z = 0; w.w = 0;
  w.x = (unsigned)h0 | ((unsigned)h1 << 16); w.y = (unsigned)h2;
  ((uint4*)&ph[(size_t)id*32])[0] = w;
  ((uint4*)&ph[(size_t)id*32])[1] = z4;
  ((uint4*)&ph[(size_t)id*32])[2] = z4;
  ((uint4*)&ph[(size_t)id*32])[3] = z4;
  w.x = (unsigned)m0 | ((unsigned)m1 << 16); w.y = (unsigned)m2;
  ((uint4*)&pm[(size_t)id*32])[0] = w;
  ((uint4*)&pm[(size_t)id*32])[1] = z4;
  ((uint4*)&pm[(size_t)id*32])[2] = z4;
  ((uint4*)&pm[(size_t)id*32])[3] = z4;
  w.x = (unsigned)l0 | ((unsigned)l1 << 16); w.y = (unsigned)l2;
  ((uint4*)&pl[(size_t)id*32])[0] = w;
  ((uint4*)&pl[(size_t)id*32])[1] = z4;
  ((uint4*)&pl[(size_t)id*32])[2] = z4;
  ((uint4*)&pl[(size_t)id*32])[3] = z4;
}

// ---------------- fused weight prep: Wa/Wd split + 3-plane cvt, combined [Wa;Wd] layout ---------
__global__ void k_prep_w6(const float* __restrict__ W, int O, int Cw, int Cout,
                          u16* __restrict__ ph, u16* __restrict__ pm, u16* __restrict__ pl){
  int id = blockIdx.x*256 + threadIdx.x;
  if (id >= O*Cout) return;
  int o = id / Cout, c = id % Cout;
  float a = 0.f, d = 0.f;
  if (c < Cw){
    a = W[(size_t)o*2*Cw + c];
    d = W[(size_t)o*2*Cw + Cw + c] - a;
  }
  u16 h, m, l;
  split3(a, h, m, l);
  ph[id] = h; pm[id] = m; pl[id] = l;
  size_t id2 = (size_t)O*Cout + id;
  split3(d, h, m, l);
  ph[id2] = h; pm[id2] = m; pl[id2] = l;
}

// ---------------- fp32 -> 2 bf16 planes, with optional on-the-fly BN for c >= cthr ----------------
__global__ void k_bn_cvt2(const float* __restrict__ in, int ld, int Cin, int Cout, int cthr,
                          const float* __restrict__ sc, const float* __restrict__ sh,
                          u16* __restrict__ ph, u16* __restrict__ pm, int total){
  int id = blockIdx.x*256 + threadIdx.x;
  if (id >= total) return;
  int r = id / Cout, c = id % Cout;
  float x = (c < Cin) ? in[(size_t)r*ld + c] : 0.f;
  if (c >= cthr) x = leakyf(fmaf(x, sc[c - cthr], sh[c - cthr]));
  u16 h = f2bf(x);
  ph[id] = h;
  pm[id] = f2bf(x - bf2f(h));
}

// ---------------- fused BN+leaky(xc, in place) + 3-plane split + NEXT-edge sqnorm ----------------
// Cout in {64,128}; total multiple of 256; rows wave-aligned.
__global__ void k_bn_cvt3s(float* __restrict__ xcs, int Cout,
                           const float* __restrict__ sc, const float* __restrict__ sh,
                           u16* __restrict__ ph, u16* __restrict__ pm, u16* __restrict__ pl,
                           float* __restrict__ xx, int total){
  __shared__ float sred[4];
  int id = blockIdx.x*256 + threadIdx.x;
  const int tid = threadIdx.x;
  float x = 0.f;
  int r = 0;
  if (id < total){
    r = id / Cout;
    int c = id % Cout;
    float* p = &xcs[(size_t)r*512 + c];
    x = leakyf(fmaf(*p, sc[c], sh[c]));
    *p = x;
    u16 h, m, l;
    split3(x, h, m, l);
    ph[id] = h; pm[id] = m; pl[id] = l;
  }
  float s = x*x;
  #pragma unroll
  for (int off = 32; off; off >>= 1) s += __shfl_xor(s, off);
  if (Cout == 64){
    if ((tid & 63) == 0 && id < total) xx[r] = s;
  } else {   // Cout == 128: two waves per row
    int wv = tid >> 6;
    if ((tid & 63) == 0) sred[wv] = s;
    __syncthreads();
    if ((tid & 127) == 0 && id < total) xx[r] = sred[wv] + sred[wv + 1];
  }
}

// ---------------- bf16-split MFMA NT GEMM, NPL planes, 128x128 tile ----------------------------
// MODE 0: store. MODE 1: pd symmetric upper-triangle (136 blocks) + LDS-transpose mirror.
// MODE 2: accumulate into C (+ fused per-channel stats). MODE 3: store + fused stats.
#define MT 128
#define KT 32
#define LDT 40   // padded row stride in u16 (80 B)

template<int MODE, int NPL>
__global__ __launch_bounds__(256)
void k_mfma_nt(const u16* __restrict__ Ah, const u16* __restrict__ Am, const u16* __restrict__ Al, long sA,
               const u16* __restrict__ Bh, const u16* __restrict__ Bm, const u16* __restrict__ Bl, long sB,
               float* __restrict__ Cm, int ldc, long sC, int K,
               const float* __restrict__ xx, long sX,
               float* __restrict__ ssum, float* __restrict__ ssq){
  __shared__ __align__(16) u16 As[NPL][MT][LDT];
  __shared__ __align__(16) u16 Bs[NPL][MT][LDT];
  const int z = blockIdx.z;
  int bx = blockIdx.x, by = blockIdx.y;
  if (MODE == 1){                         // triangle decode: blockIdx.x in [0,136)
    int tt = blockIdx.x, bi = 0;
    while (tt >= 16 - bi){ tt -= 16 - bi; ++bi; }
    bx = bi; by = bi + tt;                // bx <= by
  }
  const int m0 = bx*MT, n0 = by*MT;
  const int t = threadIdx.x;
  const int lane = t & 63, wv = t >> 6;
  const int wm = (wv >> 1)*64, wn = (wv & 1)*64;    // 2x2 wave grid, 64x64 per wave
  const int lr = lane & 15, lg = lane >> 4;

  // staging: per K-step, 2*NPL planes x 128 rows x 4 k-chunks -> 4*NPL chunks/thread
  const u16* gsrc[4*NPL];
  u16* ldst[4*NPL];
  #pragma unroll
  for (int s = 0; s < 4*NPL; ++s){
    int f = s*256 + t;
    int p = f >> 9;             // 0..NPL-1: A planes, NPL..2NPL-1: B planes
    int r = (f >> 2) & 127;
    int g = f & 3;
    const u16* base;
    int row0;
    u16* lb;
    if (p < NPL){
      base = ((p == 0) ? Ah : (p == 1) ? Am : Al) + (size_t)z*sA;
      row0 = m0;
      lb = &As[p][0][0];
    } else {
      int pb = p - NPL;
      base = ((pb == 0) ? Bh : (pb == 1) ? Bm : Bl) + (size_t)z*sB;
      row0 = n0;
      lb = &Bs[pb][0][0];
    }
    gsrc[s] = base + (size_t)(row0 + r)*K + g*8;
    ldst[s] = lb + r*LDT + g*8;
  }

  f4v acc[4][4] = {};

  // register prefetch of first tile
  s8v st[4*NPL];
  #pragma unroll
  for (int s = 0; s < 4*NPL; ++s) st[s] = *(const s8v*)(gsrc[s]);

  for (int k0 = 0; k0 < K; k0 += KT){
    __syncthreads();                       // previous tile fully consumed
    #pragma unroll
    for (int s = 0; s < 4*NPL; ++s) *(s8v*)(ldst[s]) = st[s];
    __syncthreads();
    if (k0 + KT < K){                      // issue next-tile loads before the MFMA section
      #pragma unroll
      for (int s = 0; s < 4*NPL; ++s) st[s] = *(const s8v*)(gsrc[s] + k0 + KT);
    }
    s8v bh[4], bm[4], bl[4];
    #pragma unroll
    for (int j = 0; j < 4; ++j){
      int rb = wn + j*16 + lr;
      bh[j] = *(const s8v*)&Bs[0][rb][lg*8];
      bm[j] = *(const s8v*)&Bs[1][rb][lg*8];
      if constexpr (NPL == 3) bl[j] = *(const s8v*)&Bs[2][rb][lg*8];
    }
    #pragma unroll
    for (int i = 0; i < 4; ++i){
      int ra = wm + i*16 + lr;
      s8v ah = *(const s8v*)&As[0][ra][lg*8];
      s8v am = *(const s8v*)&As[1][ra][lg*8];
      s8v al;
      if constexpr (NPL == 3) al = *(const s8v*)&As[2][ra][lg*8];
      #pragma unroll
      for (int j = 0; j < 4; ++j){
        acc[i][j] = __builtin_amdgcn_mfma_f32_16x16x32_bf16(ah, bh[j], acc[i][j], 0, 0, 0);
        acc[i][j] = __builtin_amdgcn_mfma_f32_16x16x32_bf16(ah, bm[j], acc[i][j], 0, 0, 0);
        acc[i][j] = __builtin_amdgcn_mfma_f32_16x16x32_bf16(am, bh[j], acc[i][j], 0, 0, 0);
        if constexpr (NPL == 3){
          acc[i][j] = __builtin_amdgcn_mfma_f32_16x16x32_bf16(am, bm[j], acc[i][j], 0, 0, 0);
          acc[i][j] = __builtin_amdgcn_mfma_f32_16x16x32_bf16(ah, bl[j], acc[i][j], 0, 0, 0);
          acc[i][j] = __builtin_amdgcn_mfma_f32_16x16x32_bf16(al, bh[j], acc[i][j], 0, 0, 0);
        }
      }
    }
  }

  // epilogue; C/D layout: col = lane&15, row = (lane>>4)*4 + reg
  float* Cb = Cm + (size_t)z*sC;
  float xn[4], xmr[4][4];
  if (MODE == 1){
    const float* xb = xx + (size_t)z*sX;
    #pragma unroll
    for (int j = 0; j < 4; ++j) xn[j] = xb[n0 + wn + j*16 + lr];
    #pragma unroll
    for (int i = 0; i < 4; ++i)
      #pragma unroll
      for (int q = 0; q < 4; ++q)
        xmr[i][q] = xb[m0 + wm + i*16 + lg*4 + q];
  }
  float ls[4] = {0.f,0.f,0.f,0.f}, lq[4] = {0.f,0.f,0.f,0.f};
  #pragma unroll
  for (int i = 0; i < 4; ++i){
    #pragma unroll
    for (int q = 0; q < 4; ++q){
      int m = m0 + wm + i*16 + lg*4 + q;
      #pragma unroll
      for (int j = 0; j < 4; ++j){
        int n = n0 + wn + j*16 + lr;
        float v = acc[i][j][q];
        if (MODE == 1) v = 2.f*v - xmr[i][q] - xn[j];
        if (MODE == 2) v += Cb[(size_t)m*ldc + n];
        Cb[(size_t)m*ldc + n] = v;
        if (MODE >= 2){ ls[j] += v; lq[j] = fmaf(v, v, lq[j]); }
      }
    }
  }
  if (MODE >= 2){  // fused per-channel stats (each output element counted exactly once)
    int cp = ((blockIdx.x << 3) + blockIdx.z) & (NCOPY-1);
    #pragma unroll
    for (int j = 0; j < 4; ++j){
      int n = n0 + wn + j*16 + lr;   // channel in [0,512)
      atomicAdd(&ssum[cp*512 + n], ls[j]);
      atomicAdd(&ssq[cp*512 + n], lq[j]);
    }
  }

  // symmetric mirror via LDS transpose: coalesced 512B-row writes (no RMW scatter)
  if (MODE == 1 && bx != by){
    float* T = (float*)&As[0][0][0];   // 64 x 132 floats, aliases dead staging (As+Bs)
    #pragma unroll
    for (int p = 0; p < 2; ++p){
      __syncthreads();                 // staging LDS (or prev pass) fully consumed
      #pragma unroll
      for (int jj = 0; jj < 2; ++jj){
        int j = 2*p + jj;
        int tr = (wn >> 1) + 16*jj + lr;   // row in T: buf*32 + rloc
        #pragma unroll
        for (int i = 0; i < 4; ++i){
          float4 v4;
          v4.x = 2.f*acc[i][j][0] - xmr[i][0] - xn[j];
          v4.y = 2.f*acc[i][j][1] - xmr[i][1] - xn[j];
          v4.z = 2.f*acc[i][j][2] - xmr[i][2] - xn[j];
          v4.w = 2.f*acc[i][j][3] - xmr[i][3] - xn[j];
          *(float4*)&T[(size_t)tr*132 + wm + i*16 + lg*4] = v4;
        }
      }
      __syncthreads();
      #pragma unroll
      for (int w8 = 0; w8 < 8; ++w8){
        int f = w8*256 + t;
        int r = f >> 5;                  // 0..63
        int cg = f & 31;                 // float4 column group
        int n = n0 + ((r >> 5) << 6) + p*32 + (r & 31);
        float4 v = *(float4*)&T[(size_t)r*132 + cg*4];
        *(float4*)&Cb[(size_t)n*ldc + m0 + cg*4] = v;
      }
    }
  }
}

// ---------------- head GEMM: A = fp32 xc with BN-on-the-fly (cols>=256) + split2 in staging ----
// Conversion of the NEXT tile runs in the MFMA section (VALU overlaps matrix pipe), so the
// barrier-to-barrier window holds only ds_writes (round-16 post-mortem: in-window cvt cost 16us).
__global__ __launch_bounds__(256)
void k_mfma_head(const float* __restrict__ A,                  // (B_, N_, 512) fp32
                 const float* __restrict__ scB, const float* __restrict__ shB,
                 const u16* __restrict__ Bh, const u16* __restrict__ Bm,   // W5 planes [512][512]
                 float* __restrict__ Cm,
                 float* __restrict__ ssum, float* __restrict__ ssq){
  __shared__ __align__(16) u16 As[2][MT][LDT];
  __shared__ __align__(16) u16 Bs[2][MT][LDT];
  const int z = blockIdx.z;
  const int m0 = blockIdx.x*MT, n0 = blockIdx.y*MT;
  const int t = threadIdx.x;
  const int lane = t & 63, wv = t >> 6;
  const int wm = (wv >> 1)*64, wn = (wv & 1)*64;
  const int lr = lane & 15, lg = lane >> 4;
  const float* Ab = A + (size_t)z*N_*512;

  // A: 512 fp32 8-elem chunks per K-step -> 2/thread; B: 1024 u16 chunks -> 4/thread
  int gA[2];
  const float* gsA[2];
  u16 *ldA0[2], *ldA1[2];
  #pragma unroll
  for (int s = 0; s < 2; ++s){
    int f = s*256 + t;
    int rA = f >> 2; gA[s] = f & 3;
    gsA[s] = Ab + (size_t)(m0 + rA)*512 + gA[s]*8;
    ldA0[s] = &As[0][rA][gA[s]*8];
    ldA1[s] = &As[1][rA][gA[s]*8];
  }
  const u16* gsB[4];
  u16* ldB[4];
  #pragma unroll
  for (int s = 0; s < 4; ++s){
    int f = s*256 + t;
    int p = f >> 9;
    int r = (f >> 2) & 127;
    int g = f & 3;
    gsB[s] = ((p == 0) ? Bh : Bm) + (size_t)(n0 + r)*512 + g*8;
    ldB[s] = &Bs[p][r][g*8];
  }

  f4v acc[4][4] = {};

  float4 pa[2][2];
  s8v pb[4];
  s8v ca0[2], ca1[2];    // converted A (h, m planes) for the tile about to be written

  // prefetch + convert tile 0
  #pragma unroll
  for (int s = 0; s < 2; ++s){
    pa[s][0] = *(const float4*)(gsA[s]);
    pa[s][1] = *(const float4*)(gsA[s] + 4);
  }
  #pragma unroll
  for (int s = 0; s < 4; ++s) pb[s] = *(const s8v*)(gsB[s]);
  #pragma unroll
  for (int s = 0; s < 2; ++s){           // k0=0: bn=false
    float xv[8] = {pa[s][0].x, pa[s][0].y, pa[s][0].z, pa[s][0].w,
                   pa[s][1].x, pa[s][1].y, pa[s][1].z, pa[s][1].w};
    #pragma unroll
    for (int e = 0; e < 8; ++e){
      u16 h = f2bf(xv[e]);
      ca0[s][e] = (short)h;
      ca1[s][e] = (short)f2bf(xv[e] - bf2f(h));
    }
  }

  for (int k0 = 0; k0 < 512; k0 += KT){
    __syncthreads();
    #pragma unroll
    for (int s = 0; s < 2; ++s){ *(s8v*)ldA0[s] = ca0[s]; *(s8v*)ldA1[s] = ca1[s]; }
    #pragma unroll
    for (int s = 0; s < 4; ++s) *(s8v*)(ldB[s]) = pb[s];
    __syncthreads();
    const int kn = k0 + KT;
    if (kn < 512){
      #pragma unroll
      for (int s = 0; s < 2; ++s){
        pa[s][0] = *(const float4*)(gsA[s] + kn);
        pa[s][1] = *(const float4*)(gsA[s] + kn + 4);
      }
      #pragma unroll
      for (int s = 0; s < 4; ++s) pb[s] = *(const s8v*)(gsB[s] + kn);
    }
    s8v bh[4], bm[4];
    #pragma unroll
    for (int j = 0; j < 4; ++j){
      int rb = wn + j*16 + lr;
      bh[j] = *(const s8v*)&Bs[0][rb][lg*8];
      bm[j] = *(const s8v*)&Bs[1][rb][lg*8];
    }
    // convert next tile in-register; independent of LDS reads + MFMA below -> VALU overlaps MFMA
    if (kn < 512){
      const bool bn = (kn >= 256);        // uniform: chunks never straddle col 256
      #pragma unroll
      for (int s = 0; s < 2; ++s){
        float xv[8] = {pa[s][0].x, pa[s][0].y, pa[s][0].z, pa[s][0].w,
                       pa[s][1].x, pa[s][1].y, pa[s][1].z, pa[s][1].w};
        int cb = kn + gA[s]*8 - 256;
        #pragma unroll
        for (int e = 0; e < 8; ++e){
          float xe = xv[e];
          if (bn) xe = leakyf(fmaf(xe, scB[cb + e], shB[cb + e]));
          u16 h = f2bf(xe);
          ca0[s][e] = (short)h;
          ca1[s][e] = (short)f2bf(xe - bf2f(h));
        }
      }
    }
    #pragma unroll
    for (int i = 0; i < 4; ++i){
      int ra = wm + i*16 + lr;
      s8v ah = *(const s8v*)&As[0][ra][lg*8];
      s8v am = *(const s8v*)&As[1][ra][lg*8];
      #pragma unroll
      for (int j = 0; j < 4; ++j){
        acc[i][j] = __builtin_amdgcn_mfma_f32_16x16x32_bf16(ah, bh[j], acc[i][j], 0, 0, 0);
        acc[i][j] = __builtin_amdgcn_mfma_f32_16x16x32_bf16(ah, bm[j], acc[i][j], 0, 0, 0);
        acc[i][j] = __builtin_amdgcn_mfma_f32_16x16x32_bf16(am, bh[j], acc[i][j], 0, 0, 0);
      }
    }
  }

  // MODE3 epilogue: store + fused per-channel stats
  float* Cb = Cm + (size_t)z*N_*512;
  float ls[4] = {0.f,0.f,0.f,0.f}, lq[4] = {0.f,0.f,0.f,0.f};
  #pragma unroll
  for (int i = 0; i < 4; ++i){
    #pragma unroll
    for (int q = 0; q < 4; ++q){
      int m = m0 + wm + i*16 + lg*4 + q;
      #pragma unroll
      for (int j = 0; j < 4; ++j){
        int n = n0 + wn + j*16 + lr;
        float v = acc[i][j][q];
        Cb[(size_t)m*512 + n] = v;
        ls[j] += v;
        lq[j] = fmaf(v, v, lq[j]);
      }
    }
  }
  int cp = ((blockIdx.x << 3) + blockIdx.z) & (NCOPY-1);
  #pragma unroll
  for (int j = 0; j < 4; ++j){
    int n = n0 + wn + j*16 + lr;
    atomicAdd(&ssum[cp*512 + n], ls[j]);
    atomicAdd(&ssq[cp*512 + n], lq[j]);
  }
}

// ---------------- top-20 per row: 1 WAVE per row, sample-threshold + bitonic sort ----------------
__global__ __launch_bounds__(256)
void k_topk(const float* __restrict__ pd, int b0, int* __restrict__ idx){
  __shared__ u64 skey[4][64];
  const int w = threadIdx.x >> 6, lane = threadIdx.x & 63;
  const int row = blockIdx.x*4 + w;
  const float* prow = pd + (size_t)row * N_;

  float e[32];
  #pragma unroll
  for (int q = 0; q < 8; ++q){
    float4 v4 = ((const float4*)prow)[q*64 + lane];
    e[4*q+0] = v4.x; e[4*q+1] = v4.y; e[4*q+2] = v4.z; e[4*q+3] = v4.w;
  }
  // elem index of e[q] = (q>>2)*256 + lane*4 + (q&3)

  // Phase A: per-lane max
  float lmax = e[0];
  #pragma unroll
  for (int q = 1; q < 32; ++q) lmax = fmaxf(lmax, e[q]);

  // Phase B: bitonic ascending sort of lane-maxes; t = lane 40 (24th largest)
  float sv = lmax;
  #pragma unroll
  for (int k = 2; k <= 64; k <<= 1){
    #pragma unroll
    for (int j = k >> 1; j > 0; j >>= 1){
      float o = __shfl_xor(sv, j);
      bool keepMax = (((lane & k) == 0) == ((lane & j) != 0));
      sv = keepMax ? fmaxf(sv, o) : fminf(sv, o);
    }
  }
  float t = __shfl(sv, 40);

  // Phase C: ballot-scan compaction of candidates (v > t) into LDS keys
  const u64 below = (lane == 0) ? 0ULL : (~0ULL >> (64 - lane));
  int base = 0;
  #pragma unroll
  for (int q = 0; q < 32; ++q){
    bool pred = e[q] > t;
    u64 mask = __ballot(pred);
    if (pred){
      int p = base + __popcll(mask & below);
      if (p < 64){
        int ei = (q>>2)*256 + lane*4 + (q&3);
        skey[w][p] = ((u64)fkey(e[q]) << 32) | (unsigned)(N_ - 1 - ei);
      }
    }
    base += __popcll(mask);
  }
  int C = base;
  asm volatile("s_waitcnt lgkmcnt(0)" ::: "memory");

  const int gb = b0 + row / N_;
  const int n = row % N_;
  int* out = idx + ((size_t)gb*N_ + n)*K_;

  if (C >= K_ && C <= 64){
    // Phase D: bitonic ascending sort of u64 keys; lanes 44..63 hold top-20 ascending
    u64 key = (lane < C) ? skey[w][lane] : 0ULL;
    #pragma unroll
    for (int k = 2; k <= 64; k <<= 1){
      #pragma unroll
      for (int j = k >> 1; j > 0; j >>= 1){
        u64 o = __shfl_xor(key, j);
        bool keepMax = (((lane & k) == 0) == ((lane & j) != 0));
        bool sel = (key > o) == keepMax;
        key = sel ? key : o;
      }
    }
    if (lane >= 44) out[63 - lane] = (N_ - 1) - (int)(key & 0xFFFFFFFFu);
  } else {
    // fallback: exact 20-round serial extraction over registers (rare)
    for (int tt = 0; tt < K_; ++tt){
      float best = -INFINITY; int bi = 0x7FFFFFFF;
      #pragma unroll
      for (int q = 0; q < 32; ++q){
        int iq = (q>>2)*256 + lane*4 + (q&3);
        if (e[q] > best || (e[q] == best && iq < bi)){ best = e[q]; bi = iq; }
      }
      #pragma unroll
      for (int off = 32; off; off >>= 1){
        float ov = __shfl_xor(best, off);
        int oi = __shfl_xor(bi, off);
        if (ov > best || (ov == best && oi < bi)){ best = ov; bi = oi; }
      }
      if (lane == 0) out[tt] = bi;
      #pragma unroll
      for (int q = 0; q < 32; ++q){
        int iq = (q>>2)*256 + lane*4 + (q&3);
        if (iq == bi) e[q] = -INFINITY;
      }
    }
  }
}

// ---------------- gather + max over k + BN stats; uv = [u | v] per point ----------------
// XCD-pinned (b = blockIdx&7) for L2-resident gather; NCOPY-strided atomics.
__global__ __launch_bounds__(256)
void k_edge_assemble(const float* __restrict__ uv, const int* __restrict__ idx,
                     float* __restrict__ xc, int O, int c0,
                     float* __restrict__ ssum, float* __restrict__ ssq){
  const int tid = threadIdx.x;
  const int npar = 256 / O;            // O in {64,128,256}
  const int o = tid % O;
  const int slot = tid / O;
  const int b = blockIdx.x & 7;        // batch -> XCD pin
  const int tile = blockIdx.x >> 3;    // 0 .. N_/TP_-1
  const int ld = 2*O;
  float lsum = 0.f, lsq = 0.f;
  for (int i = slot; i < TP_; i += npar){
    int n = tile*TP_ + i;
    const float vv = uv[((size_t)b*N_+n)*ld + O + o];
    const int* ip = idx + ((size_t)b*N_+n)*K_;
    float m = -INFINITY;
    #pragma unroll
    for (int kk = 0; kk < K_; ++kk){
      int j = ip[kk];
      float h = uv[((size_t)b*N_+j)*ld + o] + vv;
      m = fmaxf(m, h);
      lsum += h;
      lsq = fmaf(h, h, lsq);
    }
    xc[((size_t)b*N_+n)*512 + c0 + o] = m;
  }
  const int cp = blockIdx.x & (NCOPY-1);
  atomicAdd(&ssum[cp*O + o], lsum);
  atomicAdd(&ssq[cp*O + o], lsq);
}

// ---------------- BN scale/shift from NCOPY-strided stats ----------------
__global__ void k_bn_finalize(const float* __restrict__ ssum, const float* __restrict__ ssq,
                              const float* __restrict__ g, const float* __restrict__ bb,
                              float* __restrict__ sc, float* __restrict__ sh, int O, double cnt){
  int o = threadIdx.x;
  if (o >= O) return;
  double S1 = 0.0, S2 = 0.0;
  for (int c = 0; c < NCOPY; ++c){
    S1 += (double)ssum[c*O + o];
    S2 += (double)ssq[c*O + o];
  }
  double mean = S1 / cnt;
  double var = S2 / cnt - mean*mean;
  if (var < 0.0) var = 0.0;
  float inv = rsqrtf((float)var + EPSV);
  float s = g[o] * inv;
  sc[o] = s;
  sh[o] = bb[o] - (float)mean * s;
}

// ---------------- BN+leaky + max/mean over N, two-stage ----------------
__global__ void k_final_partial(const float* __restrict__ h5, const float* __restrict__ sc,
                                const float* __restrict__ sh, float* __restrict__ pmax,
                                float* __restrict__ psum){
  const int o = threadIdx.x;  // 512
  const int b = blockIdx.x >> 4, c = blockIdx.x & 15;
  const float s = sc[o], t = sh[o];
  float mx = -INFINITY, sm = 0.f;
  for (int i = 0; i < 128; ++i){
    int n = c*128 + i;
    float v = leakyf(fmaf(h5[((size_t)b*N_+n)*512 + o], s, t));
    mx = fmaxf(mx, v);
    sm += v;
  }
  pmax[(size_t)blockIdx.x*512 + o] = mx;
  psum[(size_t)blockIdx.x*512 + o] = sm;
}

__global__ void k_final_combine(const float* __restrict__ pmax, const float* __restrict__ psum,
                                float* __restrict__ out){
  const int o = threadIdx.x;  // 512
  const int b = blockIdx.x;
  float mx = -INFINITY, sm = 0.f;
  for (int c = 0; c < 16; ++c){
    mx = fmaxf(mx, pmax[((size_t)b*16+c)*512 + o]);
    sm += psum[((size_t)b*16+c)*512 + o];
  }
  out[(size_t)b*1024 + o] = mx;
  out[(size_t)b*1024 + 512 + o] = sm * (1.f/N_);
}

extern "C" void kernel_launch(void* const* d_in, const int* in_sizes, int n_in,
                              void* d_out, int out_size, void* d_ws, size_t ws_size,
                              hipStream_t stream){
  const float* x  = (const float*)d_in[0];
  const float* W1 = (const float*)d_in[2];
  const float* g1 = (const float*)d_in[3];
  const float* b1 = (const float*)d_in[4];
  const float* W2 = (const float*)d_in[5];
  const float* g2 = (const float*)d_in[6];
  const float* b2 = (const float*)d_in[7];
  const float* W3 = (const float*)d_in[8];
  const float* g3 = (const float*)d_in[9];
  const float* b3 = (const float*)d_in[10];
  const float* W4 = (const float*)d_in[11];
  const float* g4 = (const float*)d_in[12];
  const float* b4 = (const float*)d_in[13];
  const float* W5 = (const float*)d_in[14];
  const float* g5 = (const float*)d_in[15];
  const float* b5 = (const float*)d_in[16];
  float* out = (float*)d_out;

  // pd chunking: pick largest NB in {8,4,2} that fits the workspace
  size_t fixed_f = (size_t)B_*N_*512*2 + (size_t)B_*N_ + 2u*512 + 10u*NCOPY*512;
  size_t idxb = (size_t)B_*N_*K_*4;
  size_t need8 = (fixed_f + (size_t)8*N_*N_)*4 + idxb;
  size_t need4 = (fixed_f + (size_t)4*N_*N_)*4 + idxb;
  const int NB = (ws_size >= need8) ? 8 : (ws_size >= need4) ? 4 : 2;
  const size_t RFLOATS = (size_t)NB*N_*N_;

  // workspace bump allocation (floats)
  float* w = (float*)d_ws;
  float* xc  = w; w += (size_t)B_*N_*512;       // concat output (b,n,c) point-major
  float* h5  = w; w += (size_t)B_*N_*512;       // head GEMM output; also hosts bf16 staging
  float* R   = w; w += RFLOATS;                 // pd chunk / uv / W5 planes / pmax,psum
  float* xx  = w; w += (size_t)B_*N_;
  float* sc  = w; w += 512;
  float* sh  = w; w += 512;
  float* SS  = w; w += 10u*NCOPY*512;           // 5 stages x {ssum, ssq}
  int* idxp  = (int*)w; w += (size_t)B_*N_*K_;
  (void)in_sizes; (void)n_in; (void)out_size;

  // bf16 plane staging inside h5 region (dead until head GEMM writes h5)
  u16* Xh = (u16*)h5;                            // each plane <= B*N*128 u16
  u16* Xm = Xh + 2097152;
  u16* Xl = Xm + 2097152;
  u16* WhE = Xl + 2097152;                       // combined [Wa;Wd] planes, <= 65536 u16 each
  u16* WmE = WhE + 65536;
  u16* WlE = WmE + 65536;
  float* uv = R;
  float* pmax = R;                               // used only after R's other uses are dead
  float* psum = R + 128*512;

  // one memset for ALL stat stages (replaces 10 small memsets)
  hipMemsetAsync(SS, 0, 10u*NCOPY*512*sizeof(float), stream);

  // fused input prep: transpose + sqnorm + 3-plane split (Cout=32)
  k_in_prep<<<dim3((B_*N_)/256), dim3(256), 0, stream>>>(x, xx, Xh, Xm, Xl);

  struct Cfg { int Cw; int Cout; const float* W; const float* g; const float* bb; int O; int c0; };
  Cfg cfgs[4] = {
    { 3,   32,  W1, g1, b1, 64,  0   },
    { 64,  64,  W2, g2, b2, 64,  64  },
    { 64,  64,  W3, g3, b3, 128, 128 },
    { 128, 128, W4, g4, b4, 256, 256 },
  };

  for (int e = 0; e < 4; ++e){
    Cfg c = cfgs[e];
    float* ssumE = SS + (size_t)(2*e)*NCOPY*512;
    float* ssqE  = ssumE + (size_t)NCOPY*512;
    k_prep_w6<<<dim3((c.O*c.Cout + 255)/256), dim3(256), 0, stream>>>(
        c.W, c.O, c.Cw, c.Cout, WhE, WmE, WlE);
    long sAb = (long)N_*c.Cout;
    // pairwise distances (upper-triangle + LDS-transposed mirror) + top-k
    for (int b0 = 0; b0 < B_; b0 += NB){
      const u16* Ah = Xh + (size_t)b0*sAb;
      const u16* Am = Xm + (size_t)b0*sAb;
      const u16* Al = Xl + (size_t)b0*sAb;
      k_mfma_nt<1,3><<<dim3(136,1,NB), dim3(256), 0, stream>>>(
          Ah, Am, Al, sAb, Ah, Am, Al, sAb,
          R, N_, (long)N_*N_, c.Cout, xx + b0*N_, (long)N_, nullptr, nullptr);
      k_topk<<<dim3((NB*N_)/4), dim3(256), 0, stream>>>(R, b0, idxp);
    }
    // uv = X . [Wa;Wd]^T in one GEMM (cols 0..O-1 = u, O..2O-1 = v)
    int twoO = 2*c.O;
    k_mfma_nt<0,3><<<dim3(16, twoO/128, 8), dim3(256), 0, stream>>>(
        Xh, Xm, Xl, sAb, WhE, WmE, WlE, 0L,
        uv, twoO, (long)N_*twoO, c.Cout, nullptr, 0L, nullptr, nullptr);
    k_edge_assemble<<<dim3(B_*(N_/TP_)), dim3(256), 0, stream>>>(uv, idxp, xc, c.O, c.c0, ssumE, ssqE);
    k_bn_finalize<<<dim3(1), dim3(512), 0, stream>>>(ssumE, ssqE, c.g, c.bb, sc, sh, c.O, (double)B_*N_*K_);
    if (e < 3){
      // fused: BN+leaky in place on xc slice + next block's 3 planes + next-edge sqnorm
      int totN = B_*N_*cfgs[e+1].Cout;            // Cin==Cout for these handoffs
      k_bn_cvt3s<<<dim3((totN + 255)/256), dim3(256), 0, stream>>>(
          xc + c.c0, cfgs[e+1].Cout, sc, sh, Xh, Xm, Xl, xx, totN);
    }
    // e==3: BN for channels 256..511 applied on the fly inside the head GEMM staging
  }

  // head: h5 = xc . W5^T — fp32-A staging with fused BN+split2 (conversion overlapped with MFMA);
  // stats fused into epilogue. W5 planes pre-split (tiny, 1 MB).
  float* ssumH = SS + (size_t)8*NCOPY*512;
  float* ssqH  = ssumH + (size_t)NCOPY*512;
  if (NB >= 4){
    u16* W5h = (u16*)R;                           // 512x512 = 262144 u16 per plane
    u16* W5m = W5h + 262144;
    k_bn_cvt2<<<dim3((512*512)/256), dim3(256), 0, stream>>>(
        W5, 512, 512, 512, 512, nullptr, nullptr, W5h, W5m, 512*512);
    k_mfma_head<<<dim3(16, 4, 8), dim3(256), 0, stream>>>(
        xc, sc, sh, W5h, W5m, h5, ssumH, ssqH);
  } else {
    // two K=256 halves (fallback for small workspace), 2 planes; stats fused into MODE 2 half
    u16* Rh = (u16*)R;
    u16* Rm = Rh + 4194304;
    u16* W5h = Rm + 4194304;
    u16* W5m = W5h + 131072;
    for (int hf = 0; hf < 2; ++hf){
      int totA = B_*N_*256;
      k_bn_cvt2<<<dim3((totA)/256), dim3(256), 0, stream>>>(
          xc + hf*256, 512, 256, 256, (hf == 0) ? 256 : 0, sc, sh, Rh, Rm, totA);
      k_bn_cvt2<<<dim3((512*256)/256), dim3(256), 0, stream>>>(
          W5 + hf*256, 512, 256, 256, 256, nullptr, nullptr, W5h, W5m, 512*256);
      if (hf == 0)
        k_mfma_nt<0,2><<<dim3(16, 4, 8), dim3(256), 0, stream>>>(
            Rh, Rm, nullptr, (long)N_*256, W5h, W5m, nullptr, 0L,
            h5, 512, (long)N_*512, 256, nullptr, 0L, nullptr, nullptr);
      else
        k_mfma_nt<2,2><<<dim3(16, 4, 8), dim3(256), 0, stream>>>(
            Rh, Rm, nullptr, (long)N_*256, W5h, W5m, nullptr, 0L,
            h5, 512, (long)N_*512, 256, nullptr, 0L, ssumH, ssqH);
    }
  }
  k_bn_finalize<<<dim3(1), dim3(512), 0, stream>>>(ssumH, ssqH, g5, b5, sc, sh, 512, (double)B_*N_);
  k_final_partial<<<dim3(B_*16), dim3(512), 0, stream>>>(h5, sc, sh, pmax, psum);
  k_final_combine<<<dim3(B_), dim3(512), 0, stream>>>(pmax, psum, out);
}

// Round 18
// 564.232 us; speedup vs baseline: 1.0245x; 1.0245x over previous
//
#include <hip/hip_runtime.h>
#include <math.h>
#include <stdint.h>

#define B_ 8
#define N_ 2048
#define K_ 20
#define EPSV 1e-5f
#define SLOPEV 0.2f
#define TP_ 16     // points per edge_assemble block
#define NCOPY 32   // accumulator copies (atomic contention /32)

typedef unsigned short u16;
typedef unsigned long long u64;
typedef __attribute__((ext_vector_type(8))) short s8v;   // 8 x bf16 MFMA fragment
typedef __attribute__((ext_vector_type(4))) float f4v;   // 4 x f32 MFMA accumulator

static __device__ __forceinline__ float leakyf(float v){ return v >= 0.f ? v : SLOPEV*v; }

// float -> bf16 round-nearest-even, and back
static __device__ __forceinline__ u16 f2bf(float f){
  unsigned u = __float_as_uint(f);
  return (u16)((u + 0x7fffu + ((u >> 16) & 1u)) >> 16);
}
static __device__ __forceinline__ float bf2f(u16 h){ return __uint_as_float(((unsigned)h) << 16); }

// monotonic float->uint key (ascending)
static __device__ __forceinline__ unsigned fkey(float f){
  unsigned u = __float_as_uint(f);
  return u ^ ((u >> 31) ? 0xFFFFFFFFu : 0x80000000u);
}

static __device__ __forceinline__ void split3(float x, u16& h, u16& m, u16& l){
  h = f2bf(x);
  float r1 = x - bf2f(h);        // exact (Sterbenz)
  m = f2bf(r1);
  l = f2bf(r1 - bf2f(m));
}

// ---------------- fused input prep: transpose (B,3,N) + sqnorm + 3-plane split (Cout=32) --------
__global__ void k_in_prep(const float* __restrict__ x, float* __restrict__ xx,
                          u16* __restrict__ ph, u16* __restrict__ pm, u16* __restrict__ pl){
  int id = blockIdx.x*256 + threadIdx.x;
  if (id >= B_*N_) return;
  int b = id / N_, n = id % N_;
  float v0 = x[((size_t)b*3+0)*N_ + n];
  float v1 = x[((size_t)b*3+1)*N_ + n];
  float v2 = x[((size_t)b*3+2)*N_ + n];
  xx[id] = fmaf(v2, v2, fmaf(v1, v1, v0*v0));   // same order as old serial sqnorm
  u16 h0,m0,l0,h1,m1,l1,h2,m2,l2;
  split3(v0,h0,m0,l0); split3(v1,h1,m1,l1); split3(v2,h2,m2,l2);
  uint4 z4 = {0,0,0,0};
  uint4 w;
  w.z = 0; w.w = 0;
  w.x = (unsigned)h0 | ((unsigned)h1 << 16); w.y = (unsigned)h2;
  ((uint4*)&ph[(size_t)id*32])[0] = w;
  ((uint4*)&ph[(size_t)id*32])[1] = z4;
  ((uint4*)&ph[(size_t)id*32])[2] = z4;
  ((uint4*)&ph[(size_t)id*32])[3] = z4;
  w.x = (unsigned)m0 | ((unsigned)m1 << 16); w.y = (unsigned)m2;
  ((uint4*)&pm[(size_t)id*32])[0] = w;
  ((uint4*)&pm[(size_t)id*32])[1] = z4;
  ((uint4*)&pm[(size_t)id*32])[2] = z4;
  ((uint4*)&pm[(size_t)id*32])[3] = z4;
  w.x = (unsigned)l0 | ((unsigned)l1 << 16); w.y = (unsigned)l2;
  ((uint4*)&pl[(size_t)id*32])[0] = w;
  ((uint4*)&pl[(size_t)id*32])[1] = z4;
  ((uint4*)&pl[(size_t)id*32])[2] = z4;
  ((uint4*)&pl[(size_t)id*32])[3] = z4;
}

// ---------------- fused weight prep: Wa/Wd split + 3-plane cvt, combined [Wa;Wd] layout ---------
__global__ void k_prep_w6(const float* __restrict__ W, int O, int Cw, int Cout,
                          u16* __restrict__ ph, u16* __restrict__ pm, u16* __restrict__ pl){
  int id = blockIdx.x*256 + threadIdx.x;
  if (id >= O*Cout) return;
  int o = id / Cout, c = id % Cout;
  float a = 0.f, d = 0.f;
  if (c < Cw){
    a = W[(size_t)o*2*Cw + c];
    d = W[(size_t)o*2*Cw + Cw + c] - a;
  }
  u16 h, m, l;
  split3(a, h, m, l);
  ph[id] = h; pm[id] = m; pl[id] = l;
  size_t id2 = (size_t)O*Cout + id;
  split3(d, h, m, l);
  ph[id2] = h; pm[id2] = m; pl[id2] = l;
}

// ---------------- fp32 -> 2 bf16 planes, with optional on-the-fly BN for c >= cthr ----------------
__global__ void k_bn_cvt2(const float* __restrict__ in, int ld, int Cin, int Cout, int cthr,
                          const float* __restrict__ sc, const float* __restrict__ sh,
                          u16* __restrict__ ph, u16* __restrict__ pm, int total){
  int id = blockIdx.x*256 + threadIdx.x;
  if (id >= total) return;
  int r = id / Cout, c = id % Cout;
  float x = (c < Cin) ? in[(size_t)r*ld + c] : 0.f;
  if (c >= cthr) x = leakyf(fmaf(x, sc[c - cthr], sh[c - cthr]));
  u16 h = f2bf(x);
  ph[id] = h;
  pm[id] = f2bf(x - bf2f(h));
}

// ---------------- fused BN+leaky(xc, in place) + 3-plane split + NEXT-edge sqnorm ----------------
// Cout in {64,128}; total multiple of 256; rows wave-aligned.
__global__ void k_bn_cvt3s(float* __restrict__ xcs, int Cout,
                           const float* __restrict__ sc, const float* __restrict__ sh,
                           u16* __restrict__ ph, u16* __restrict__ pm, u16* __restrict__ pl,
                           float* __restrict__ xx, int total){
  __shared__ float sred[4];
  int id = blockIdx.x*256 + threadIdx.x;
  const int tid = threadIdx.x;
  float x = 0.f;
  int r = 0;
  if (id < total){
    r = id / Cout;
    int c = id % Cout;
    float* p = &xcs[(size_t)r*512 + c];
    x = leakyf(fmaf(*p, sc[c], sh[c]));
    *p = x;
    u16 h, m, l;
    split3(x, h, m, l);
    ph[id] = h; pm[id] = m; pl[id] = l;
  }
  float s = x*x;
  #pragma unroll
  for (int off = 32; off; off >>= 1) s += __shfl_xor(s, off);
  if (Cout == 64){
    if ((tid & 63) == 0 && id < total) xx[r] = s;
  } else {   // Cout == 128: two waves per row
    int wv = tid >> 6;
    if ((tid & 63) == 0) sred[wv] = s;
    __syncthreads();
    if ((tid & 127) == 0 && id < total) xx[r] = sred[wv] + sred[wv + 1];
  }
}

// ---------------- bf16-split MFMA NT GEMM, NPL planes, 128x128 tile ----------------------------
// MODE 0: store. MODE 1: pd symmetric upper-triangle (136 blocks) + LDS-transpose mirror.
// MODE 2: accumulate into C (+ fused per-channel stats). MODE 3: store + fused stats.
#define MT 128
#define KT 32
#define LDT 40   // padded row stride in u16 (80 B)

template<int MODE, int NPL>
__global__ __launch_bounds__(256)
void k_mfma_nt(const u16* __restrict__ Ah, const u16* __restrict__ Am, const u16* __restrict__ Al, long sA,
               const u16* __restrict__ Bh, const u16* __restrict__ Bm, const u16* __restrict__ Bl, long sB,
               float* __restrict__ Cm, int ldc, long sC, int K,
               const float* __restrict__ xx, long sX,
               float* __restrict__ ssum, float* __restrict__ ssq){
  __shared__ __align__(16) u16 As[NPL][MT][LDT];
  __shared__ __align__(16) u16 Bs[NPL][MT][LDT];
  const int z = blockIdx.z;
  int bx = blockIdx.x, by = blockIdx.y;
  if (MODE == 1){                         // triangle decode: blockIdx.x in [0,136)
    int tt = blockIdx.x, bi = 0;
    while (tt >= 16 - bi){ tt -= 16 - bi; ++bi; }
    bx = bi; by = bi + tt;                // bx <= by
  }
  const int m0 = bx*MT, n0 = by*MT;
  const int t = threadIdx.x;
  const int lane = t & 63, wv = t >> 6;
  const int wm = (wv >> 1)*64, wn = (wv & 1)*64;    // 2x2 wave grid, 64x64 per wave
  const int lr = lane & 15, lg = lane >> 4;

  // staging: per K-step, 2*NPL planes x 128 rows x 4 k-chunks -> 4*NPL chunks/thread
  const u16* gsrc[4*NPL];
  u16* ldst[4*NPL];
  #pragma unroll
  for (int s = 0; s < 4*NPL; ++s){
    int f = s*256 + t;
    int p = f >> 9;             // 0..NPL-1: A planes, NPL..2NPL-1: B planes
    int r = (f >> 2) & 127;
    int g = f & 3;
    const u16* base;
    int row0;
    u16* lb;
    if (p < NPL){
      base = ((p == 0) ? Ah : (p == 1) ? Am : Al) + (size_t)z*sA;
      row0 = m0;
      lb = &As[p][0][0];
    } else {
      int pb = p - NPL;
      base = ((pb == 0) ? Bh : (pb == 1) ? Bm : Bl) + (size_t)z*sB;
      row0 = n0;
      lb = &Bs[pb][0][0];
    }
    gsrc[s] = base + (size_t)(row0 + r)*K + g*8;
    ldst[s] = lb + r*LDT + g*8;
  }

  f4v acc[4][4] = {};

  // register prefetch of first tile
  s8v st[4*NPL];
  #pragma unroll
  for (int s = 0; s < 4*NPL; ++s) st[s] = *(const s8v*)(gsrc[s]);

  for (int k0 = 0; k0 < K; k0 += KT){
    __syncthreads();                       // previous tile fully consumed
    #pragma unroll
    for (int s = 0; s < 4*NPL; ++s) *(s8v*)(ldst[s]) = st[s];
    __syncthreads();
    if (k0 + KT < K){                      // issue next-tile loads before the MFMA section
      #pragma unroll
      for (int s = 0; s < 4*NPL; ++s) st[s] = *(const s8v*)(gsrc[s] + k0 + KT);
    }
    s8v bh[4], bm[4], bl[4];
    #pragma unroll
    for (int j = 0; j < 4; ++j){
      int rb = wn + j*16 + lr;
      bh[j] = *(const s8v*)&Bs[0][rb][lg*8];
      bm[j] = *(const s8v*)&Bs[1][rb][lg*8];
      if constexpr (NPL == 3) bl[j] = *(const s8v*)&Bs[2][rb][lg*8];
    }
    #pragma unroll
    for (int i = 0; i < 4; ++i){
      int ra = wm + i*16 + lr;
      s8v ah = *(const s8v*)&As[0][ra][lg*8];
      s8v am = *(const s8v*)&As[1][ra][lg*8];
      s8v al;
      if constexpr (NPL == 3) al = *(const s8v*)&As[2][ra][lg*8];
      #pragma unroll
      for (int j = 0; j < 4; ++j){
        acc[i][j] = __builtin_amdgcn_mfma_f32_16x16x32_bf16(ah, bh[j], acc[i][j], 0, 0, 0);
        acc[i][j] = __builtin_amdgcn_mfma_f32_16x16x32_bf16(ah, bm[j], acc[i][j], 0, 0, 0);
        acc[i][j] = __builtin_amdgcn_mfma_f32_16x16x32_bf16(am, bh[j], acc[i][j], 0, 0, 0);
        if constexpr (NPL == 3){
          acc[i][j] = __builtin_amdgcn_mfma_f32_16x16x32_bf16(am, bm[j], acc[i][j], 0, 0, 0);
          acc[i][j] = __builtin_amdgcn_mfma_f32_16x16x32_bf16(ah, bl[j], acc[i][j], 0, 0, 0);
          acc[i][j] = __builtin_amdgcn_mfma_f32_16x16x32_bf16(al, bh[j], acc[i][j], 0, 0, 0);
        }
      }
    }
  }

  // epilogue; C/D layout: col = lane&15, row = (lane>>4)*4 + reg
  float* Cb = Cm + (size_t)z*sC;
  float xn[4], xmr[4][4];
  if (MODE == 1){
    const float* xb = xx + (size_t)z*sX;
    #pragma unroll
    for (int j = 0; j < 4; ++j) xn[j] = xb[n0 + wn + j*16 + lr];
    #pragma unroll
    for (int i = 0; i < 4; ++i)
      #pragma unroll
      for (int q = 0; q < 4; ++q)
        xmr[i][q] = xb[m0 + wm + i*16 + lg*4 + q];
  }
  float ls[4] = {0.f,0.f,0.f,0.f}, lq[4] = {0.f,0.f,0.f,0.f};
  #pragma unroll
  for (int i = 0; i < 4; ++i){
    #pragma unroll
    for (int q = 0; q < 4; ++q){
      int m = m0 + wm + i*16 + lg*4 + q;
      #pragma unroll
      for (int j = 0; j < 4; ++j){
        int n = n0 + wn + j*16 + lr;
        float v = acc[i][j][q];
        if (MODE == 1) v = 2.f*v - xmr[i][q] - xn[j];
        if (MODE == 2) v += Cb[(size_t)m*ldc + n];
        Cb[(size_t)m*ldc + n] = v;
        if (MODE >= 2){ ls[j] += v; lq[j] = fmaf(v, v, lq[j]); }
      }
    }
  }
  if (MODE >= 2){  // fused per-channel stats (each output element counted exactly once)
    int cp = ((blockIdx.x << 3) + blockIdx.z) & (NCOPY-1);
    #pragma unroll
    for (int j = 0; j < 4; ++j){
      int n = n0 + wn + j*16 + lr;   // channel in [0,512)
      atomicAdd(&ssum[cp*512 + n], ls[j]);
      atomicAdd(&ssq[cp*512 + n], lq[j]);
    }
  }

  // symmetric mirror via LDS transpose: coalesced 512B-row writes (no RMW scatter)
  if (MODE == 1 && bx != by){
    float* T = (float*)&As[0][0][0];   // 64 x 132 floats, aliases dead staging (As+Bs)
    #pragma unroll
    for (int p = 0; p < 2; ++p){
      __syncthreads();                 // staging LDS (or prev pass) fully consumed
      #pragma unroll
      for (int jj = 0; jj < 2; ++jj){
        int j = 2*p + jj;
        int tr = (wn >> 1) + 16*jj + lr;   // row in T: buf*32 + rloc
        #pragma unroll
        for (int i = 0; i < 4; ++i){
          float4 v4;
          v4.x = 2.f*acc[i][j][0] - xmr[i][0] - xn[j];
          v4.y = 2.f*acc[i][j][1] - xmr[i][1] - xn[j];
          v4.z = 2.f*acc[i][j][2] - xmr[i][2] - xn[j];
          v4.w = 2.f*acc[i][j][3] - xmr[i][3] - xn[j];
          *(float4*)&T[(size_t)tr*132 + wm + i*16 + lg*4] = v4;
        }
      }
      __syncthreads();
      #pragma unroll
      for (int w8 = 0; w8 < 8; ++w8){
        int f = w8*256 + t;
        int r = f >> 5;                  // 0..63
        int cg = f & 31;                 // float4 column group
        int n = n0 + ((r >> 5) << 6) + p*32 + (r & 31);
        float4 v = *(float4*)&T[(size_t)r*132 + cg*4];
        *(float4*)&Cb[(size_t)n*ldc + m0 + cg*4] = v;
      }
    }
  }
}

// ---------------- head GEMM: A = fp32 xc with BN-on-the-fly (cols>=256) + split2 in staging ----
// h5[m][n] = sum_k A'[m][k]*W5[n][k], bf16x2 (3-MFMA), MODE3 epilogue (store + fused stats).
// Produces bit-identical h5 to the old k_bn_cvt2 + k_mfma_nt<3,2> pipeline, minus 67MB traffic.
__global__ __launch_bounds__(256)
void k_mfma_head(const float* __restrict__ A,                  // (B_, N_, 512) fp32
                 const float* __restrict__ scB, const float* __restrict__ shB,
                 const u16* __restrict__ Bh, const u16* __restrict__ Bm,   // W5 planes [512][512]
                 float* __restrict__ Cm,
                 float* __restrict__ ssum, float* __restrict__ ssq){
  __shared__ __align__(16) u16 As[2][MT][LDT];
  __shared__ __align__(16) u16 Bs[2][MT][LDT];
  const int z = blockIdx.z;
  const int m0 = blockIdx.x*MT, n0 = blockIdx.y*MT;
  const int t = threadIdx.x;
  const int lane = t & 63, wv = t >> 6;
  const int wm = (wv >> 1)*64, wn = (wv & 1)*64;
  const int lr = lane & 15, lg = lane >> 4;
  const float* Ab = A + (size_t)z*N_*512;

  // A: 512 fp32 8-elem chunks per K-step -> 2/thread; B: 1024 u16 chunks -> 4/thread
  int gA[2];
  const float* gsA[2];
  u16 *ldA0[2], *ldA1[2];
  #pragma unroll
  for (int s = 0; s < 2; ++s){
    int f = s*256 + t;
    int rA = f >> 2; gA[s] = f & 3;
    gsA[s] = Ab + (size_t)(m0 + rA)*512 + gA[s]*8;
    ldA0[s] = &As[0][rA][gA[s]*8];
    ldA1[s] = &As[1][rA][gA[s]*8];
  }
  const u16* gsB[4];
  u16* ldB[4];
  #pragma unroll
  for (int s = 0; s < 4; ++s){
    int f = s*256 + t;
    int p = f >> 9;
    int r = (f >> 2) & 127;
    int g = f & 3;
    gsB[s] = ((p == 0) ? Bh : Bm) + (size_t)(n0 + r)*512 + g*8;
    ldB[s] = &Bs[p][r][g*8];
  }

  f4v acc[4][4] = {};

  float4 pa[2][2];
  s8v pb[4];
  #pragma unroll
  for (int s = 0; s < 2; ++s){
    pa[s][0] = *(const float4*)(gsA[s]);
    pa[s][1] = *(const float4*)(gsA[s] + 4);
  }
  #pragma unroll
  for (int s = 0; s < 4; ++s) pb[s] = *(const s8v*)(gsB[s]);

  for (int k0 = 0; k0 < 512; k0 += KT){
    __syncthreads();
    const bool bn = (k0 >= 256);          // uniform: chunks never straddle col 256
    #pragma unroll
    for (int s = 0; s < 2; ++s){
      float xv[8] = {pa[s][0].x, pa[s][0].y, pa[s][0].z, pa[s][0].w,
                     pa[s][1].x, pa[s][1].y, pa[s][1].z, pa[s][1].w};
      s8v hv, mv;
      int cb = k0 + gA[s]*8 - 256;
      #pragma unroll
      for (int e = 0; e < 8; ++e){
        float xe = xv[e];
        if (bn) xe = leakyf(fmaf(xe, scB[cb + e], shB[cb + e]));
        u16 h = f2bf(xe);
        hv[e] = (short)h;
        mv[e] = (short)f2bf(xe - bf2f(h));
      }
      *(s8v*)ldA0[s] = hv;
      *(s8v*)ldA1[s] = mv;
    }
    #pragma unroll
    for (int s = 0; s < 4; ++s) *(s8v*)(ldB[s]) = pb[s];
    __syncthreads();
    if (k0 + KT < 512){
      #pragma unroll
      for (int s = 0; s < 2; ++s){
        pa[s][0] = *(const float4*)(gsA[s] + k0 + KT);
        pa[s][1] = *(const float4*)(gsA[s] + k0 + KT + 4);
      }
      #pragma unroll
      for (int s = 0; s < 4; ++s) pb[s] = *(const s8v*)(gsB[s] + k0 + KT);
    }
    s8v bh[4], bm[4];
    #pragma unroll
    for (int j = 0; j < 4; ++j){
      int rb = wn + j*16 + lr;
      bh[j] = *(const s8v*)&Bs[0][rb][lg*8];
      bm[j] = *(const s8v*)&Bs[1][rb][lg*8];
    }
    #pragma unroll
    for (int i = 0; i < 4; ++i){
      int ra = wm + i*16 + lr;
      s8v ah = *(const s8v*)&As[0][ra][lg*8];
      s8v am = *(const s8v*)&As[1][ra][lg*8];
      #pragma unroll
      for (int j = 0; j < 4; ++j){
        acc[i][j] = __builtin_amdgcn_mfma_f32_16x16x32_bf16(ah, bh[j], acc[i][j], 0, 0, 0);
        acc[i][j] = __builtin_amdgcn_mfma_f32_16x16x32_bf16(ah, bm[j], acc[i][j], 0, 0, 0);
        acc[i][j] = __builtin_amdgcn_mfma_f32_16x16x32_bf16(am, bh[j], acc[i][j], 0, 0, 0);
      }
    }
  }

  // MODE3 epilogue: store + fused per-channel stats
  float* Cb = Cm + (size_t)z*N_*512;
  float ls[4] = {0.f,0.f,0.f,0.f}, lq[4] = {0.f,0.f,0.f,0.f};
  #pragma unroll
  for (int i = 0; i < 4; ++i){
    #pragma unroll
    for (int q = 0; q < 4; ++q){
      int m = m0 + wm + i*16 + lg*4 + q;
      #pragma unroll
      for (int j = 0; j < 4; ++j){
        int n = n0 + wn + j*16 + lr;
        float v = acc[i][j][q];
        Cb[(size_t)m*512 + n] = v;
        ls[j] += v;
        lq[j] = fmaf(v, v, lq[j]);
      }
    }
  }
  int cp = ((blockIdx.x << 3) + blockIdx.z) & (NCOPY-1);
  #pragma unroll
  for (int j = 0; j < 4; ++j){
    int n = n0 + wn + j*16 + lr;
    atomicAdd(&ssum[cp*512 + n], ls[j]);
    atomicAdd(&ssq[cp*512 + n], lq[j]);
  }
}

// ---------------- top-20 per row: 1 WAVE per row, sample-threshold + bitonic sort ----------------
__global__ __launch_bounds__(256)
void k_topk(const float* __restrict__ pd, int b0, int* __restrict__ idx){
  __shared__ u64 skey[4][64];
  const int w = threadIdx.x >> 6, lane = threadIdx.x & 63;
  const int row = blockIdx.x*4 + w;
  const float* prow = pd + (size_t)row * N_;

  float e[32];
  #pragma unroll
  for (int q = 0; q < 8; ++q){
    float4 v4 = ((const float4*)prow)[q*64 + lane];
    e[4*q+0] = v4.x; e[4*q+1] = v4.y; e[4*q+2] = v4.z; e[4*q+3] = v4.w;
  }
  // elem index of e[q] = (q>>2)*256 + lane*4 + (q&3)

  // Phase A: per-lane max
  float lmax = e[0];
  #pragma unroll
  for (int q = 1; q < 32; ++q) lmax = fmaxf(lmax, e[q]);

  // Phase B: bitonic ascending sort of lane-maxes; t = lane 40 (24th largest)
  float sv = lmax;
  #pragma unroll
  for (int k = 2; k <= 64; k <<= 1){
    #pragma unroll
    for (int j = k >> 1; j > 0; j >>= 1){
      float o = __shfl_xor(sv, j);
      bool keepMax = (((lane & k) == 0) == ((lane & j) != 0));
      sv = keepMax ? fmaxf(sv, o) : fminf(sv, o);
    }
  }
  float t = __shfl(sv, 40);

  // Phase C: ballot-scan compaction of candidates (v > t) into LDS keys
  const u64 below = (lane == 0) ? 0ULL : (~0ULL >> (64 - lane));
  int base = 0;
  #pragma unroll
  for (int q = 0; q < 32; ++q){
    bool pred = e[q] > t;
    u64 mask = __ballot(pred);
    if (pred){
      int p = base + __popcll(mask & below);
      if (p < 64){
        int ei = (q>>2)*256 + lane*4 + (q&3);
        skey[w][p] = ((u64)fkey(e[q]) << 32) | (unsigned)(N_ - 1 - ei);
      }
    }
    base += __popcll(mask);
  }
  int C = base;
  asm volatile("s_waitcnt lgkmcnt(0)" ::: "memory");

  const int gb = b0 + row / N_;
  const int n = row % N_;
  int* out = idx + ((size_t)gb*N_ + n)*K_;

  if (C >= K_ && C <= 64){
    // Phase D: bitonic ascending sort of u64 keys; lanes 44..63 hold top-20 ascending
    u64 key = (lane < C) ? skey[w][lane] : 0ULL;
    #pragma unroll
    for (int k = 2; k <= 64; k <<= 1){
      #pragma unroll
      for (int j = k >> 1; j > 0; j >>= 1){
        u64 o = __shfl_xor(key, j);
        bool keepMax = (((lane & k) == 0) == ((lane & j) != 0));
        bool sel = (key > o) == keepMax;
        key = sel ? key : o;
      }
    }
    if (lane >= 44) out[63 - lane] = (N_ - 1) - (int)(key & 0xFFFFFFFFu);
  } else {
    // fallback: exact 20-round serial extraction over registers (rare)
    for (int tt = 0; tt < K_; ++tt){
      float best = -INFINITY; int bi = 0x7FFFFFFF;
      #pragma unroll
      for (int q = 0; q < 32; ++q){
        int iq = (q>>2)*256 + lane*4 + (q&3);
        if (e[q] > best || (e[q] == best && iq < bi)){ best = e[q]; bi = iq; }
      }
      #pragma unroll
      for (int off = 32; off; off >>= 1){
        float ov = __shfl_xor(best, off);
        int oi = __shfl_xor(bi, off);
        if (ov > best || (ov == best && oi < bi)){ best = ov; bi = oi; }
      }
      if (lane == 0) out[tt] = bi;
      #pragma unroll
      for (int q = 0; q < 32; ++q){
        int iq = (q>>2)*256 + lane*4 + (q&3);
        if (iq == bi) e[q] = -INFINITY;
      }
    }
  }
}

// ---------------- gather + max over k + BN stats; uv = [u | v] per point ----------------
// XCD-pinned (b = blockIdx&7) for L2-resident gather; NCOPY-strided atomics.
__global__ __launch_bounds__(256)
void k_edge_assemble(const float* __restrict__ uv, const int* __restrict__ idx,
                     float* __restrict__ xc, int O, int c0,
                     float* __restrict__ ssum, float* __restrict__ ssq){
  const int tid = threadIdx.x;
  const int npar = 256 / O;            // O in {64,128,256}
  const int o = tid % O;
  const int slot = tid / O;
  const int b = blockIdx.x & 7;        // batch -> XCD pin
  const int tile = blockIdx.x >> 3;    // 0 .. N_/TP_-1
  const int ld = 2*O;
  float lsum = 0.f, lsq = 0.f;
  for (int i = slot; i < TP_; i += npar){
    int n = tile*TP_ + i;
    const float vv = uv[((size_t)b*N_+n)*ld + O + o];
    const int* ip = idx + ((size_t)b*N_+n)*K_;
    float m = -INFINITY;
    #pragma unroll
    for (int kk = 0; kk < K_; ++kk){
      int j = ip[kk];
      float h = uv[((size_t)b*N_+j)*ld + o] + vv;
      m = fmaxf(m, h);
      lsum += h;
      lsq = fmaf(h, h, lsq);
    }
    xc[((size_t)b*N_+n)*512 + c0 + o] = m;
  }
  const int cp = blockIdx.x & (NCOPY-1);
  atomicAdd(&ssum[cp*O + o], lsum);
  atomicAdd(&ssq[cp*O + o], lsq);
}

// ---------------- BN scale/shift from NCOPY-strided stats ----------------
__global__ void k_bn_finalize(const float* __restrict__ ssum, const float* __restrict__ ssq,
                              const float* __restrict__ g, const float* __restrict__ bb,
                              float* __restrict__ sc, float* __restrict__ sh, int O, double cnt){
  int o = threadIdx.x;
  if (o >= O) return;
  double S1 = 0.0, S2 = 0.0;
  for (int c = 0; c < NCOPY; ++c){
    S1 += (double)ssum[c*O + o];
    S2 += (double)ssq[c*O + o];
  }
  double mean = S1 / cnt;
  double var = S2 / cnt - mean*mean;
  if (var < 0.0) var = 0.0;
  float inv = rsqrtf((float)var + EPSV);
  float s = g[o] * inv;
  sc[o] = s;
  sh[o] = bb[o] - (float)mean * s;
}

// ---------------- BN+leaky + max/mean over N, two-stage ----------------
__global__ void k_final_partial(const float* __restrict__ h5, const float* __restrict__ sc,
                                const float* __restrict__ sh, float* __restrict__ pmax,
                                float* __restrict__ psum){
  const int o = threadIdx.x;  // 512
  const int b = blockIdx.x >> 4, c = blockIdx.x & 15;
  const float s = sc[o], t = sh[o];
  float mx = -INFINITY, sm = 0.f;
  for (int i = 0; i < 128; ++i){
    int n = c*128 + i;
    float v = leakyf(fmaf(h5[((size_t)b*N_+n)*512 + o], s, t));
    mx = fmaxf(mx, v);
    sm += v;
  }
  pmax[(size_t)blockIdx.x*512 + o] = mx;
  psum[(size_t)blockIdx.x*512 + o] = sm;
}

__global__ void k_final_combine(const float* __restrict__ pmax, const float* __restrict__ psum,
                                float* __restrict__ out){
  const int o = threadIdx.x;  // 512
  const int b = blockIdx.x;
  float mx = -INFINITY, sm = 0.f;
  for (int c = 0; c < 16; ++c){
    mx = fmaxf(mx, pmax[((size_t)b*16+c)*512 + o]);
    sm += psum[((size_t)b*16+c)*512 + o];
  }
  out[(size_t)b*1024 + o] = mx;
  out[(size_t)b*1024 + 512 + o] = sm * (1.f/N_);
}

extern "C" void kernel_launch(void* const* d_in, const int* in_sizes, int n_in,
                              void* d_out, int out_size, void* d_ws, size_t ws_size,
                              hipStream_t stream){
  const float* x  = (const float*)d_in[0];
  const float* W1 = (const float*)d_in[2];
  const float* g1 = (const float*)d_in[3];
  const float* b1 = (const float*)d_in[4];
  const float* W2 = (const float*)d_in[5];
  const float* g2 = (const float*)d_in[6];
  const float* b2 = (const float*)d_in[7];
  const float* W3 = (const float*)d_in[8];
  const float* g3 = (const float*)d_in[9];
  const float* b3 = (const float*)d_in[10];
  const float* W4 = (const float*)d_in[11];
  const float* g4 = (const float*)d_in[12];
  const float* b4 = (const float*)d_in[13];
  const float* W5 = (const float*)d_in[14];
  const float* g5 = (const float*)d_in[15];
  const float* b5 = (const float*)d_in[16];
  float* out = (float*)d_out;

  // pd chunking: pick largest NB in {8,4,2} that fits the workspace
  size_t fixed_f = (size_t)B_*N_*512*2 + (size_t)B_*N_ + 2u*512 + 10u*NCOPY*512;
  size_t idxb = (size_t)B_*N_*K_*4;
  size_t need8 = (fixed_f + (size_t)8*N_*N_)*4 + idxb;
  size_t need4 = (fixed_f + (size_t)4*N_*N_)*4 + idxb;
  const int NB = (ws_size >= need8) ? 8 : (ws_size >= need4) ? 4 : 2;
  const size_t RFLOATS = (size_t)NB*N_*N_;

  // workspace bump allocation (floats)
  float* w = (float*)d_ws;
  float* xc  = w; w += (size_t)B_*N_*512;       // concat output (b,n,c) point-major
  float* h5  = w; w += (size_t)B_*N_*512;       // head GEMM output; also hosts bf16 staging
  float* R   = w; w += RFLOATS;                 // pd chunk / uv / W5 planes / pmax,psum
  float* xx  = w; w += (size_t)B_*N_;
  float* sc  = w; w += 512;
  float* sh  = w; w += 512;
  float* SS  = w; w += 10u*NCOPY*512;           // 5 stages x {ssum, ssq}
  int* idxp  = (int*)w; w += (size_t)B_*N_*K_;
  (void)in_sizes; (void)n_in; (void)out_size;

  // bf16 plane staging inside h5 region (dead until head GEMM writes h5)
  u16* Xh = (u16*)h5;                            // each plane <= B*N*128 u16
  u16* Xm = Xh + 2097152;
  u16* Xl = Xm + 2097152;
  u16* WhE = Xl + 2097152;                       // combined [Wa;Wd] planes, <= 65536 u16 each
  u16* WmE = WhE + 65536;
  u16* WlE = WmE + 65536;
  float* uv = R;
  float* pmax = R;                               // used only after R's other uses are dead
  float* psum = R + 128*512;

  // one memset for ALL stat stages (replaces 10 small memsets)
  hipMemsetAsync(SS, 0, 10u*NCOPY*512*sizeof(float), stream);

  // fused input prep: transpose + sqnorm + 3-plane split (Cout=32)
  k_in_prep<<<dim3((B_*N_)/256), dim3(256), 0, stream>>>(x, xx, Xh, Xm, Xl);

  struct Cfg { int Cw; int Cout; const float* W; const float* g; const float* bb; int O; int c0; };
  Cfg cfgs[4] = {
    { 3,   32,  W1, g1, b1, 64,  0   },
    { 64,  64,  W2, g2, b2, 64,  64  },
    { 64,  64,  W3, g3, b3, 128, 128 },
    { 128, 128, W4, g4, b4, 256, 256 },
  };

  for (int e = 0; e < 4; ++e){
    Cfg c = cfgs[e];
    float* ssumE = SS + (size_t)(2*e)*NCOPY*512;
    float* ssqE  = ssumE + (size_t)NCOPY*512;
    k_prep_w6<<<dim3((c.O*c.Cout + 255)/256), dim3(256), 0, stream>>>(
        c.W, c.O, c.Cw, c.Cout, WhE, WmE, WlE);
    long sAb = (long)N_*c.Cout;
    // pairwise distances (upper-triangle + LDS-transposed mirror) + top-k
    for (int b0 = 0; b0 < B_; b0 += NB){
      const u16* Ah = Xh + (size_t)b0*sAb;
      const u16* Am = Xm + (size_t)b0*sAb;
      const u16* Al = Xl + (size_t)b0*sAb;
      k_mfma_nt<1,3><<<dim3(136,1,NB), dim3(256), 0, stream>>>(
          Ah, Am, Al, sAb, Ah, Am, Al, sAb,
          R, N_, (long)N_*N_, c.Cout, xx + b0*N_, (long)N_, nullptr, nullptr);
      k_topk<<<dim3((NB*N_)/4), dim3(256), 0, stream>>>(R, b0, idxp);
    }
    // uv = X . [Wa;Wd]^T in one GEMM (cols 0..O-1 = u, O..2O-1 = v)
    int twoO = 2*c.O;
    k_mfma_nt<0,3><<<dim3(16, twoO/128, 8), dim3(256), 0, stream>>>(
        Xh, Xm, Xl, sAb, WhE, WmE, WlE, 0L,
        uv, twoO, (long)N_*twoO, c.Cout, nullptr, 0L, nullptr, nullptr);
    k_edge_assemble<<<dim3(B_*(N_/TP_)), dim3(256), 0, stream>>>(uv, idxp, xc, c.O, c.c0, ssumE, ssqE);
    k_bn_finalize<<<dim3(1), dim3(512), 0, stream>>>(ssumE, ssqE, c.g, c.bb, sc, sh, c.O, (double)B_*N_*K_);
    if (e < 3){
      // fused: BN+leaky in place on xc slice + next block's 3 planes + next-edge sqnorm
      int totN = B_*N_*cfgs[e+1].Cout;            // Cin==Cout for these handoffs
      k_bn_cvt3s<<<dim3((totN + 255)/256), dim3(256), 0, stream>>>(
          xc + c.c0, cfgs[e+1].Cout, sc, sh, Xh, Xm, Xl, xx, totN);
    }
    // e==3: BN for channels 256..511 applied on the fly inside the head GEMM staging
  }

  // head: h5 = xc . W5^T — fp32-A staging with fused BN+split2 (no separate cvt pass);
  // stats fused into epilogue. W5 planes pre-split (tiny, 1 MB).
  float* ssumH = SS + (size_t)8*NCOPY*512;
  float* ssqH  = ssumH + (size_t)NCOPY*512;
  if (NB >= 4){
    u16* W5h = (u16*)R;                           // 512x512 = 262144 u16 per plane
    u16* W5m = W5h + 262144;
    k_bn_cvt2<<<dim3((512*512)/256), dim3(256), 0, stream>>>(
        W5, 512, 512, 512, 512, nullptr, nullptr, W5h, W5m, 512*512);
    k_mfma_head<<<dim3(16, 4, 8), dim3(256), 0, stream>>>(
        xc, sc, sh, W5h, W5m, h5, ssumH, ssqH);
  } else {
    // two K=256 halves (fallback for small workspace), 2 planes; stats fused into MODE 2 half
    u16* Rh = (u16*)R;
    u16* Rm = Rh + 4194304;
    u16* W5h = Rm + 4194304;
    u16* W5m = W5h + 131072;
    for (int hf = 0; hf < 2; ++hf){
      int totA = B_*N_*256;
      k_bn_cvt2<<<dim3((totA)/256), dim3(256), 0, stream>>>(
          xc + hf*256, 512, 256, 256, (hf == 0) ? 256 : 0, sc, sh, Rh, Rm, totA);
      k_bn_cvt2<<<dim3((512*256)/256), dim3(256), 0, stream>>>(
          W5 + hf*256, 512, 256, 256, 256, nullptr, nullptr, W5h, W5m, 512*256);
      if (hf == 0)
        k_mfma_nt<0,2><<<dim3(16, 4, 8), dim3(256), 0, stream>>>(
            Rh, Rm, nullptr, (long)N_*256, W5h, W5m, nullptr, 0L,
            h5, 512, (long)N_*512, 256, nullptr, 0L, nullptr, nullptr);
      else
        k_mfma_nt<2,2><<<dim3(16, 4, 8), dim3(256), 0, stream>>>(
            Rh, Rm, nullptr, (long)N_*256, W5h, W5m, nullptr, 0L,
            h5, 512, (long)N_*512, 256, nullptr, 0L, ssumH, ssqH);
    }
  }
  k_bn_finalize<<<dim3(1), dim3(512), 0, stream>>>(ssumH, ssqH, g5, b5, sc, sh, 512, (double)B_*N_);
  k_final_partial<<<dim3(B_*16), dim3(512), 0, stream>>>(h5, sc, sh, pmax, psum);
  k_final_combine<<<dim3(B_), dim3(512), 0, stream>>>(pmax, psum, out);
}